// Round 6
// baseline (111.096 us; speedup 1.0000x reference)
//
#include <hip/hip_runtime.h>

#define H     300
#define MID   100
#define NN    1024
#define NP1   1025
#define JST   1088   // padded j-extent of E4 (E4[25][1088][4] floats)

typedef float v2f __attribute__((ext_vector_type(2)));
static __device__ __forceinline__ v2f sp2(float s) { return (v2f){s, s}; }
static __device__ __forceinline__ v2f fma2(v2f a, v2f b, v2f c) {
    return __builtin_elementwise_fma(a, b, c);
}

// 16-lane-row rotate-add via DPP (VALU pipe, no DS traffic).
template <int CTRL>
static __device__ __forceinline__ float row_ror_add(float v) {
    const int s = __builtin_amdgcn_update_dpp(0, __float_as_int(v), CTRL, 0xF, 0xF, true);
    return v + __int_as_float(s);
}
// lane ^ 16 exchange-add (single DS-pipe swizzle, stays within 32-lane group)
static __device__ __forceinline__ float swz_xor16_add(float v) {
    const int s = __builtin_amdgcn_ds_swizzle(__float_as_int(v), 0x401F);
    return v + __int_as_float(s);
}
// full 32-lane-group sum: 1 ds_swizzle + 4 DPP row_ror adds
static __device__ __forceinline__ float red32(float v) {
    v = swz_xor16_add(v);
    v = row_ror_add<0x128>(v);   // row_ror:8
    v = row_ror_add<0x124>(v);   // row_ror:4
    v = row_ror_add<0x122>(v);   // row_ror:2
    v = row_ror_add<0x121>(v);   // row_ror:1
    return v;
}

// ---------------------------------------------------------------------------
// Kernel A: byte-identical to round 5. PROBE ROUND: launched 3x (idempotent —
// all writes are deterministic overwrites; replicas precede B so results are
// bit-identical). (dur - 91.6)/2 = A_dur + launch_overhead, distinguishing
// "kernels are small, window is harness fills" (expect ~100-108 us) from
// "A is ~20-25 us and occupancy-insensitive" (expect ~132-142 us).
// ---------------------------------------------------------------------------
__global__ __launch_bounds__(1024, 8) void precompute_kernel(
    const float* __restrict__ sentence,
    const float* __restrict__ W1,
    const float* __restrict__ b1,
    float* __restrict__ Fg,
    float* __restrict__ E4,
    float* __restrict__ out)
{
    const int tid = threadIdx.x;
    const int iA = blockIdx.x * 2, iB = iA + 1;
    const float NL = -1.4426950408889634f;

    if (blockIdx.x == 0) {
        if (tid == 0) out[0] = 0.0f;                              // loss accumulator
        if (tid < MID)
            E4[(long)((tid >> 2) * JST) * 4 + (tid & 3)] = 1.0f;  // j=0 column
    }

    const int grp = tid >> 5;         // 0..31 (32-lane group)
    const int hb  = tid & 31;         // h-lane within the group

    // Loop-invariant sentence values -> registers (coalesced 128B group reads)
    const float* sA = sentence + (long)iA * H + hb;
    const float* sB = sentence + (long)iB * H + hb;
    float ra[9], rb[9];
    #pragma unroll
    for (int k = 0; k < 9; ++k) { ra[k] = sA[32 * k]; rb[k] = sB[32 * k]; }
    const bool tl = hb < 12;                       // tail lanes (h = 288+hb < 300)
    const float ra9 = tl ? sA[288] : 0.0f;         // predicated load (OOB-safe)
    const float rb9 = tl ? sB[288] : 0.0f;
    const int h9 = 288 + (tl ? hb : 0);            // clamped tail index (in-bounds)

    for (int s = 0; s < 7; ++s) {
        const int p  = s * 32 + grp;                     // 0..223
        const int pc = p < 200 ? p : 199;                // clamp keeps loads in-bounds
        const int m  = pc >> 1, half = pc & 1;
        const float* wrow = W1 + (long)m * (2 * H) + half * H;

        float aA, aB;
        {
            const float w0 = wrow[hb];
            aA = w0 * ra[0];
            aB = w0 * rb[0];
        }
        #pragma unroll
        for (int k = 1; k < 9; ++k) {
            const float w = wrow[hb + 32 * k];
            aA = __builtin_fmaf(w, ra[k], aA);
            aB = __builtin_fmaf(w, rb[k], aB);
        }
        {
            const float w9 = wrow[h9];                   // ra9/rb9 zeroed for non-tail lanes
            aA = __builtin_fmaf(w9, ra9, aA);
            aB = __builtin_fmaf(w9, rb9, aB);
        }

        aA = red32(aA);
        aB = red32(aB);

        if (hb == 0 && p < 200) {
            if (half == 0) {
                const float bb = b1[m];
                Fg[iA * MID + m] = __builtin_amdgcn_exp2f((aA + bb) * NL);
                Fg[iB * MID + m] = __builtin_amdgcn_exp2f((aB + bb) * NL);
            } else {
                float* base = E4 + (long)((m >> 2) * JST) * 4 + (m & 3);
                base[(long)(iA + 1) * 4] = __builtin_amdgcn_exp2f(aA * NL);
                base[(long)(iB + 1) * 4] = __builtin_amdgcn_exp2f(aB * NL);
            }
        }
    }
}

// ---------------------------------------------------------------------------
// Kernel B: byte-identical to rounds 4/5.
// ---------------------------------------------------------------------------
__global__ __launch_bounds__(512, 4) void main_kernel(
    const float* __restrict__ Fg,
    const float* __restrict__ E4,
    const float* __restrict__ W2,
    const float* __restrict__ b2,
    const int*   __restrict__ target,
    float* __restrict__ out)
{
    __shared__ v2f    Fq2[MID];         // {F_row0, F_row1}[m]
    __shared__ float4 w4sh[MID / 4];    // W2 m-quads
    __shared__ float  tmp[2][104];      // remainder-column partials per row
    __shared__ float  redl[8];
    __shared__ v2f    redm[8];
    __shared__ v2f    rede[8];
    __shared__ float  sc4sh[2];
    __shared__ v2f    bmax2, binv2;

    const int i0  = blockIdx.x * 2;
    const int tid = threadIdx.x;
    const int lane = tid & 63, wv = tid >> 6;
    const float L2E = 1.4426950408889634f;
    const v2f one2 = sp2(1.0f);

    if (tid < MID) {
        Fq2[tid] = (v2f){Fg[(i0 + 0) * MID + tid], Fg[(i0 + 1) * MID + tid]};
    } else if (tid >= 128 && tid < 128 + MID / 4) {
        const int p = tid - 128;
        w4sh[p] = make_float4(W2[4 * p], W2[4 * p + 1], W2[4 * p + 2], W2[4 * p + 3]);
    }
    const float b2v = b2[0];
    __syncthreads();

    // coalesced: column j reads float4 at E4 + (p*JST + j)*4
    #define LDXA(p_) (*(const float4*)(E4 + ((long)(p_) * JST + tid) * 4))
    #define LDXB(p_) (*(const float4*)(E4 + ((long)(p_) * JST + tid + 512) * 4))

    v2f acca = sp2(0.f);    // {row0,row1} for col A
    v2f accb = sp2(0.f);    // {row0,row1} for col B

    #define QCOL(X, acc)                                                      \
        do {                                                                  \
            const v2f A = fma2(sp2((X).x), F0, one2);                         \
            const v2f B = fma2(sp2((X).y), F1, one2);                         \
            const v2f C = fma2(sp2((X).z), F2, one2);                         \
            const v2f D = fma2(sp2((X).w), F3, one2);                         \
            const v2f AB = A * B, CD = C * D, P = AB * CD;                    \
            const v2f R = {__builtin_amdgcn_rcpf(P.x),                        \
                           __builtin_amdgcn_rcpf(P.y)};                       \
            const v2f n1 = fma2(w0, B, w1 * A);                               \
            const v2f n2 = fma2(w2v, D, w3 * C);                              \
            acc = fma2(fma2(n1, CD, n2 * AB), R, acc);                        \
        } while (0)

    #define QBODY(p_, XA, XB)                                                 \
        do {                                                                  \
            const v2f F0 = Fq2[4 * (p_)];                                     \
            const v2f F1 = Fq2[4 * (p_) + 1];                                 \
            const v2f F2 = Fq2[4 * (p_) + 2];                                 \
            const v2f F3 = Fq2[4 * (p_) + 3];                                 \
            const float4 w = w4sh[p_];                                        \
            const v2f w0 = sp2(w.x), w1 = sp2(w.y);                           \
            const v2f w2v = sp2(w.z), w3 = sp2(w.w);                          \
            QCOL(XA, acca);                                                   \
            QCOL(XB, accb);                                                   \
        } while (0)

    // 25 m-quads, distance-2 software pipeline on the float4 loads
    float4 xa0 = LDXA(0), xb0 = LDXB(0);
    float4 xa1 = LDXA(1), xb1 = LDXB(1);
    #pragma unroll 2
    for (int p = 0; p < 23; ++p) {
        const float4 xan = LDXA(p + 2), xbn = LDXB(p + 2);
        QBODY(p, xa0, xb0);
        xa0 = xa1; xa1 = xan;
        xb0 = xb1; xb1 = xbn;
    }
    QBODY(23, xa0, xb0);
    QBODY(24, xa1, xb1);

    const float sc0a = acca.x + b2v, sc1a = acca.y + b2v;   // col A, rows 0,1
    const float sc0b = accb.x + b2v, sc1b = accb.y + b2v;   // col B, rows 0,1

    // ---- remainder column j = 1024 (2 rows) ----
    if (tid < MID) {
        const float E = E4[((long)(tid >> 2) * JST + 1024) * 4 + (tid & 3)];
        const v2f F = Fq2[tid];
        const float wm = W2[tid];
        tmp[0][tid] = wm * __builtin_amdgcn_rcpf(__builtin_fmaf(E, F.x, 1.f));
        tmp[1][tid] = wm * __builtin_amdgcn_rcpf(__builtin_fmaf(E, F.y, 1.f));
    }
    __syncthreads();
    if (wv < 2) {
        float v = tmp[wv][lane] + ((lane < MID - 64) ? tmp[wv][lane + 64] : 0.f);
        #pragma unroll
        for (int off = 32; off > 0; off >>= 1) v += __shfl_down(v, off);
        if (lane == 0) sc4sh[wv] = v + b2v;
    }
    __syncthreads();

    // ---- loss + row-max (both columns folded per thread) ----
    const int tg0 = target[i0], tg1 = target[i0 + 1];
    const int jb = tid + 512;
    float ls = fabsf(sc0a - ((tid == tg0) ? 1.f : 0.f))
             + fabsf(sc1a - ((tid == tg1) ? 1.f : 0.f))
             + fabsf(sc0b - ((jb == tg0) ? 1.f : 0.f))
             + fabsf(sc1b - ((jb == tg1) ? 1.f : 0.f));
    v2f mx = {fmaxf(sc0a, sc0b), fmaxf(sc1a, sc1b)};
    if (tid == 0) {
        ls += fabsf(sc4sh[0] - ((1024 == tg0) ? 1.f : 0.f))
            + fabsf(sc4sh[1] - ((1024 == tg1) ? 1.f : 0.f));
        mx.x = fmaxf(mx.x, sc4sh[0]);
        mx.y = fmaxf(mx.y, sc4sh[1]);
    }
    #pragma unroll
    for (int off = 32; off > 0; off >>= 1) {
        ls += __shfl_down(ls, off);
        mx.x = fmaxf(mx.x, __shfl_down(mx.x, off));
        mx.y = fmaxf(mx.y, __shfl_down(mx.y, off));
    }
    if (lane == 0) { redl[wv] = ls; redm[wv] = mx; }
    __syncthreads();
    if (tid == 0) {
        float L = 0.f;
        v2f M = {-1e30f, -1e30f};
        #pragma unroll
        for (int k = 0; k < 8; ++k) {
            L += redl[k];
            M.x = fmaxf(M.x, redm[k].x);
            M.y = fmaxf(M.y, redm[k].y);
        }
        atomicAdd(out, L * (1.0f / ((float)NN * (float)NP1)));
        bmax2 = M;
    }
    __syncthreads();
    const v2f rm = bmax2;

    // ---- exp + sum per row (both columns) ----
    const float e0a = __builtin_amdgcn_exp2f((sc0a - rm.x) * L2E);
    const float e1a = __builtin_amdgcn_exp2f((sc1a - rm.y) * L2E);
    const float e0b = __builtin_amdgcn_exp2f((sc0b - rm.x) * L2E);
    const float e1b = __builtin_amdgcn_exp2f((sc1b - rm.y) * L2E);
    v2f e4v = sp2(0.f);
    if (tid == 0) {
        e4v.x = __builtin_amdgcn_exp2f((sc4sh[0] - rm.x) * L2E);
        e4v.y = __builtin_amdgcn_exp2f((sc4sh[1] - rm.y) * L2E);
    }
    v2f es = {e0a + e0b + e4v.x, e1a + e1b + e4v.y};
    #pragma unroll
    for (int off = 32; off > 0; off >>= 1) {
        es.x += __shfl_down(es.x, off);
        es.y += __shfl_down(es.y, off);
    }
    if (lane == 0) rede[wv] = es;
    __syncthreads();
    if (tid == 0) {
        v2f S = sp2(0.f);
        #pragma unroll
        for (int k = 0; k < 8; ++k) { S.x += rede[k].x; S.y += rede[k].y; }
        binv2 = (v2f){1.f / S.x, 1.f / S.y};
    }
    __syncthreads();
    const v2f iv = binv2;

    // ---- write softmax rows (both columns) ----
    float* o0 = out + 1 + (long)(i0 + 0) * NP1;
    float* o1 = out + 1 + (long)(i0 + 1) * NP1;
    o0[tid] = e0a * iv.x;
    o1[tid] = e1a * iv.y;
    o0[jb] = e0b * iv.x;
    o1[jb] = e1b * iv.y;
    if (tid == 0) {
        o0[1024] = e4v.x * iv.x;
        o1[1024] = e4v.y * iv.y;
    }
    #undef QBODY
    #undef QCOL
    #undef LDXA
    #undef LDXB
}

extern "C" void kernel_launch(void* const* d_in, const int* in_sizes, int n_in,
                              void* d_out, int out_size, void* d_ws, size_t ws_size,
                              hipStream_t stream) {
    const float* sentence = (const float*)d_in[0];
    const int*   target   = (const int*)  d_in[1];
    const float* W1       = (const float*)d_in[2];
    const float* b1       = (const float*)d_in[3];
    const float* W2       = (const float*)d_in[4];
    const float* b2       = (const float*)d_in[5];
    float* out = (float*)d_out;

    float* Fg = (float*)d_ws;                  // 1024*100 floats (F = exp(-s1))
    float* E4 = Fg + NN * MID;                 // 25*1088*4 floats

    // PROBE: A launched 3x (idempotent). (dur - 91.6)/2 = A_dur + launch_ovh.
    precompute_kernel<<<NN / 2, 1024, 0, stream>>>(sentence, W1, b1, Fg, E4, out);
    precompute_kernel<<<NN / 2, 1024, 0, stream>>>(sentence, W1, b1, Fg, E4, out);
    precompute_kernel<<<NN / 2, 1024, 0, stream>>>(sentence, W1, b1, Fg, E4, out);
    main_kernel<<<NN / 2, 512, 0, stream>>>(Fg, E4, W2, b2, target, out);
}

// Round 7
// 91.194 us; speedup vs baseline: 1.2182x; 1.2182x over previous
//
#include <hip/hip_runtime.h>

#define H     300
#define MID   100
#define NN    1024
#define NP1   1025
#define JST   1088   // padded j-extent of E4 (E4[25][1088][4] floats)

typedef float v2f __attribute__((ext_vector_type(2)));
static __device__ __forceinline__ v2f sp2(float s) { return (v2f){s, s}; }
static __device__ __forceinline__ v2f fma2(v2f a, v2f b, v2f c) {
    return __builtin_elementwise_fma(a, b, c);
}

// 16-lane-row rotate-add via DPP (VALU pipe, no DS traffic).
template <int CTRL>
static __device__ __forceinline__ float row_ror_add(float v) {
    const int s = __builtin_amdgcn_update_dpp(0, __float_as_int(v), CTRL, 0xF, 0xF, true);
    return v + __int_as_float(s);
}
// lane ^ 16 exchange-add (single DS-pipe swizzle, stays within 32-lane group)
static __device__ __forceinline__ float swz_xor16_add(float v) {
    const int s = __builtin_amdgcn_ds_swizzle(__float_as_int(v), 0x401F);
    return v + __int_as_float(s);
}
// full 32-lane-group sum: 1 ds_swizzle + 4 DPP row_ror adds
static __device__ __forceinline__ float red32(float v) {
    v = swz_xor16_add(v);
    v = row_ror_add<0x128>(v);   // row_ror:8
    v = row_ror_add<0x124>(v);   // row_ror:4
    v = row_ror_add<0x122>(v);   // row_ror:2
    v = row_ror_add<0x121>(v);   // row_ror:1
    return v;
}

// ---------------------------------------------------------------------------
// Kernel A: 256 blocks x 1024 threads; block b -> items i0=4b..4b+3.
// R6 probe: A+overhead = 9.75us, occupancy-insensitive (R5) -> L2-BW-bound
// on W1 re-reads. This version amortizes each W1 load over 4 items (was 2):
// total W1 L2 traffic 123 MB -> 61 MB (floor ~1.8us). 32 lane-groups; step s
// gives group (m,half) pair p = s*32+grp (200 pairs, 7 steps). Sentence rows
// in REGISTERS (40/thread). Per-item dot partition / FMA order / reduction
// tree bit-identical to R4-R6 -> absmax must stay exactly 7.629395e-06.
// half==0 -> Fg[i*MID+m] = exp2(-s1*log2e); half==1 -> E4 column (j=item+1).
// ---------------------------------------------------------------------------
__global__ __launch_bounds__(1024, 4) void precompute_kernel(
    const float* __restrict__ sentence,
    const float* __restrict__ W1,
    const float* __restrict__ b1,
    float* __restrict__ Fg,
    float* __restrict__ E4,
    float* __restrict__ out)
{
    const int tid = threadIdx.x;
    const int i0 = blockIdx.x * 4;
    const float NL = -1.4426950408889634f;

    if (blockIdx.x == 0) {
        if (tid == 0) out[0] = 0.0f;                              // loss accumulator
        if (tid < MID)
            E4[(long)((tid >> 2) * JST) * 4 + (tid & 3)] = 1.0f;  // j=0 column
    }

    const int grp = tid >> 5;         // 0..31 (32-lane group)
    const int hb  = tid & 31;         // h-lane within the group

    // Loop-invariant sentence values -> registers (coalesced 128B group reads)
    const float* s0 = sentence + (long)(i0 + 0) * H + hb;
    const float* s1 = sentence + (long)(i0 + 1) * H + hb;
    const float* s2 = sentence + (long)(i0 + 2) * H + hb;
    const float* s3 = sentence + (long)(i0 + 3) * H + hb;
    float r0[10], r1[10], r2[10], r3[10];
    #pragma unroll
    for (int k = 0; k < 9; ++k) {
        r0[k] = s0[32 * k]; r1[k] = s1[32 * k];
        r2[k] = s2[32 * k]; r3[k] = s3[32 * k];
    }
    const bool tl = hb < 12;                       // tail lanes (h = 288+hb < 300)
    r0[9] = tl ? s0[288] : 0.0f;                   // predicated loads (OOB-safe)
    r1[9] = tl ? s1[288] : 0.0f;
    r2[9] = tl ? s2[288] : 0.0f;
    r3[9] = tl ? s3[288] : 0.0f;
    const int h9 = 288 + (tl ? hb : 0);            // clamped tail index (in-bounds)

    for (int s = 0; s < 7; ++s) {
        const int p  = s * 32 + grp;                     // 0..223
        const int pc = p < 200 ? p : 199;                // clamp keeps loads in-bounds
        const int m  = pc >> 1, half = pc & 1;
        const float* wrow = W1 + (long)m * (2 * H) + half * H;

        float a0, a1, a2, a3;
        {
            const float w = wrow[hb];
            a0 = w * r0[0]; a1 = w * r1[0]; a2 = w * r2[0]; a3 = w * r3[0];
        }
        #pragma unroll
        for (int k = 1; k < 9; ++k) {
            const float w = wrow[hb + 32 * k];
            a0 = __builtin_fmaf(w, r0[k], a0);
            a1 = __builtin_fmaf(w, r1[k], a1);
            a2 = __builtin_fmaf(w, r2[k], a2);
            a3 = __builtin_fmaf(w, r3[k], a3);
        }
        {
            const float w = wrow[h9];                    // r*[9] zeroed on non-tail lanes
            a0 = __builtin_fmaf(w, r0[9], a0);
            a1 = __builtin_fmaf(w, r1[9], a1);
            a2 = __builtin_fmaf(w, r2[9], a2);
            a3 = __builtin_fmaf(w, r3[9], a3);
        }

        a0 = red32(a0); a1 = red32(a1); a2 = red32(a2); a3 = red32(a3);

        if (hb == 0 && p < 200) {
            if (half == 0) {
                const float bb = b1[m];
                Fg[(i0 + 0) * MID + m] = __builtin_amdgcn_exp2f((a0 + bb) * NL);
                Fg[(i0 + 1) * MID + m] = __builtin_amdgcn_exp2f((a1 + bb) * NL);
                Fg[(i0 + 2) * MID + m] = __builtin_amdgcn_exp2f((a2 + bb) * NL);
                Fg[(i0 + 3) * MID + m] = __builtin_amdgcn_exp2f((a3 + bb) * NL);
            } else {
                float* base = E4 + (long)((m >> 2) * JST) * 4 + (m & 3);
                base[(long)(i0 + 1) * 4] = __builtin_amdgcn_exp2f(a0 * NL);
                base[(long)(i0 + 2) * 4] = __builtin_amdgcn_exp2f(a1 * NL);
                base[(long)(i0 + 3) * 4] = __builtin_amdgcn_exp2f(a2 * NL);
                base[(long)(i0 + 4) * 4] = __builtin_amdgcn_exp2f(a3 * NL);
            }
        }
    }
}

// ---------------------------------------------------------------------------
// Kernel B: byte-identical to rounds 4-6 (proven neutral to all tweaks;
// est. 3-5us, near its L2/VALU floor).
// ---------------------------------------------------------------------------
__global__ __launch_bounds__(512, 4) void main_kernel(
    const float* __restrict__ Fg,
    const float* __restrict__ E4,
    const float* __restrict__ W2,
    const float* __restrict__ b2,
    const int*   __restrict__ target,
    float* __restrict__ out)
{
    __shared__ v2f    Fq2[MID];         // {F_row0, F_row1}[m]
    __shared__ float4 w4sh[MID / 4];    // W2 m-quads
    __shared__ float  tmp[2][104];      // remainder-column partials per row
    __shared__ float  redl[8];
    __shared__ v2f    redm[8];
    __shared__ v2f    rede[8];
    __shared__ float  sc4sh[2];
    __shared__ v2f    bmax2, binv2;

    const int i0  = blockIdx.x * 2;
    const int tid = threadIdx.x;
    const int lane = tid & 63, wv = tid >> 6;
    const float L2E = 1.4426950408889634f;
    const v2f one2 = sp2(1.0f);

    if (tid < MID) {
        Fq2[tid] = (v2f){Fg[(i0 + 0) * MID + tid], Fg[(i0 + 1) * MID + tid]};
    } else if (tid >= 128 && tid < 128 + MID / 4) {
        const int p = tid - 128;
        w4sh[p] = make_float4(W2[4 * p], W2[4 * p + 1], W2[4 * p + 2], W2[4 * p + 3]);
    }
    const float b2v = b2[0];
    __syncthreads();

    // coalesced: column j reads float4 at E4 + (p*JST + j)*4
    #define LDXA(p_) (*(const float4*)(E4 + ((long)(p_) * JST + tid) * 4))
    #define LDXB(p_) (*(const float4*)(E4 + ((long)(p_) * JST + tid + 512) * 4))

    v2f acca = sp2(0.f);    // {row0,row1} for col A
    v2f accb = sp2(0.f);    // {row0,row1} for col B

    #define QCOL(X, acc)                                                      \
        do {                                                                  \
            const v2f A = fma2(sp2((X).x), F0, one2);                         \
            const v2f B = fma2(sp2((X).y), F1, one2);                         \
            const v2f C = fma2(sp2((X).z), F2, one2);                         \
            const v2f D = fma2(sp2((X).w), F3, one2);                         \
            const v2f AB = A * B, CD = C * D, P = AB * CD;                    \
            const v2f R = {__builtin_amdgcn_rcpf(P.x),                        \
                           __builtin_amdgcn_rcpf(P.y)};                       \
            const v2f n1 = fma2(w0, B, w1 * A);                               \
            const v2f n2 = fma2(w2v, D, w3 * C);                              \
            acc = fma2(fma2(n1, CD, n2 * AB), R, acc);                        \
        } while (0)

    #define QBODY(p_, XA, XB)                                                 \
        do {                                                                  \
            const v2f F0 = Fq2[4 * (p_)];                                     \
            const v2f F1 = Fq2[4 * (p_) + 1];                                 \
            const v2f F2 = Fq2[4 * (p_) + 2];                                 \
            const v2f F3 = Fq2[4 * (p_) + 3];                                 \
            const float4 w = w4sh[p_];                                        \
            const v2f w0 = sp2(w.x), w1 = sp2(w.y);                           \
            const v2f w2v = sp2(w.z), w3 = sp2(w.w);                          \
            QCOL(XA, acca);                                                   \
            QCOL(XB, accb);                                                   \
        } while (0)

    // 25 m-quads, distance-2 software pipeline on the float4 loads
    float4 xa0 = LDXA(0), xb0 = LDXB(0);
    float4 xa1 = LDXA(1), xb1 = LDXB(1);
    #pragma unroll 2
    for (int p = 0; p < 23; ++p) {
        const float4 xan = LDXA(p + 2), xbn = LDXB(p + 2);
        QBODY(p, xa0, xb0);
        xa0 = xa1; xa1 = xan;
        xb0 = xb1; xb1 = xbn;
    }
    QBODY(23, xa0, xb0);
    QBODY(24, xa1, xb1);

    const float sc0a = acca.x + b2v, sc1a = acca.y + b2v;   // col A, rows 0,1
    const float sc0b = accb.x + b2v, sc1b = accb.y + b2v;   // col B, rows 0,1

    // ---- remainder column j = 1024 (2 rows) ----
    if (tid < MID) {
        const float E = E4[((long)(tid >> 2) * JST + 1024) * 4 + (tid & 3)];
        const v2f F = Fq2[tid];
        const float wm = W2[tid];
        tmp[0][tid] = wm * __builtin_amdgcn_rcpf(__builtin_fmaf(E, F.x, 1.f));
        tmp[1][tid] = wm * __builtin_amdgcn_rcpf(__builtin_fmaf(E, F.y, 1.f));
    }
    __syncthreads();
    if (wv < 2) {
        float v = tmp[wv][lane] + ((lane < MID - 64) ? tmp[wv][lane + 64] : 0.f);
        #pragma unroll
        for (int off = 32; off > 0; off >>= 1) v += __shfl_down(v, off);
        if (lane == 0) sc4sh[wv] = v + b2v;
    }
    __syncthreads();

    // ---- loss + row-max (both columns folded per thread) ----
    const int tg0 = target[i0], tg1 = target[i0 + 1];
    const int jb = tid + 512;
    float ls = fabsf(sc0a - ((tid == tg0) ? 1.f : 0.f))
             + fabsf(sc1a - ((tid == tg1) ? 1.f : 0.f))
             + fabsf(sc0b - ((jb == tg0) ? 1.f : 0.f))
             + fabsf(sc1b - ((jb == tg1) ? 1.f : 0.f));
    v2f mx = {fmaxf(sc0a, sc0b), fmaxf(sc1a, sc1b)};
    if (tid == 0) {
        ls += fabsf(sc4sh[0] - ((1024 == tg0) ? 1.f : 0.f))
            + fabsf(sc4sh[1] - ((1024 == tg1) ? 1.f : 0.f));
        mx.x = fmaxf(mx.x, sc4sh[0]);
        mx.y = fmaxf(mx.y, sc4sh[1]);
    }
    #pragma unroll
    for (int off = 32; off > 0; off >>= 1) {
        ls += __shfl_down(ls, off);
        mx.x = fmaxf(mx.x, __shfl_down(mx.x, off));
        mx.y = fmaxf(mx.y, __shfl_down(mx.y, off));
    }
    if (lane == 0) { redl[wv] = ls; redm[wv] = mx; }
    __syncthreads();
    if (tid == 0) {
        float L = 0.f;
        v2f M = {-1e30f, -1e30f};
        #pragma unroll
        for (int k = 0; k < 8; ++k) {
            L += redl[k];
            M.x = fmaxf(M.x, redm[k].x);
            M.y = fmaxf(M.y, redm[k].y);
        }
        atomicAdd(out, L * (1.0f / ((float)NN * (float)NP1)));
        bmax2 = M;
    }
    __syncthreads();
    const v2f rm = bmax2;

    // ---- exp + sum per row (both columns) ----
    const float e0a = __builtin_amdgcn_exp2f((sc0a - rm.x) * L2E);
    const float e1a = __builtin_amdgcn_exp2f((sc1a - rm.y) * L2E);
    const float e0b = __builtin_amdgcn_exp2f((sc0b - rm.x) * L2E);
    const float e1b = __builtin_amdgcn_exp2f((sc1b - rm.y) * L2E);
    v2f e4v = sp2(0.f);
    if (tid == 0) {
        e4v.x = __builtin_amdgcn_exp2f((sc4sh[0] - rm.x) * L2E);
        e4v.y = __builtin_amdgcn_exp2f((sc4sh[1] - rm.y) * L2E);
    }
    v2f es = {e0a + e0b + e4v.x, e1a + e1b + e4v.y};
    #pragma unroll
    for (int off = 32; off > 0; off >>= 1) {
        es.x += __shfl_down(es.x, off);
        es.y += __shfl_down(es.y, off);
    }
    if (lane == 0) rede[wv] = es;
    __syncthreads();
    if (tid == 0) {
        v2f S = sp2(0.f);
        #pragma unroll
        for (int k = 0; k < 8; ++k) { S.x += rede[k].x; S.y += rede[k].y; }
        binv2 = (v2f){1.f / S.x, 1.f / S.y};
    }
    __syncthreads();
    const v2f iv = binv2;

    // ---- write softmax rows (both columns) ----
    float* o0 = out + 1 + (long)(i0 + 0) * NP1;
    float* o1 = out + 1 + (long)(i0 + 1) * NP1;
    o0[tid] = e0a * iv.x;
    o1[tid] = e1a * iv.y;
    o0[jb] = e0b * iv.x;
    o1[jb] = e1b * iv.y;
    if (tid == 0) {
        o0[1024] = e4v.x * iv.x;
        o1[1024] = e4v.y * iv.y;
    }
    #undef QBODY
    #undef QCOL
    #undef LDXA
    #undef LDXB
}

extern "C" void kernel_launch(void* const* d_in, const int* in_sizes, int n_in,
                              void* d_out, int out_size, void* d_ws, size_t ws_size,
                              hipStream_t stream) {
    const float* sentence = (const float*)d_in[0];
    const int*   target   = (const int*)  d_in[1];
    const float* W1       = (const float*)d_in[2];
    const float* b1       = (const float*)d_in[3];
    const float* W2       = (const float*)d_in[4];
    const float* b2       = (const float*)d_in[5];
    float* out = (float*)d_out;

    float* Fg = (float*)d_ws;                  // 1024*100 floats (F = exp(-s1))
    float* E4 = Fg + NN * MID;                 // 25*1088*4 floats

    precompute_kernel<<<NN / 4, 1024, 0, stream>>>(sentence, W1, b1, Fg, E4, out);
    main_kernel<<<NN / 2, 512, 0, stream>>>(Fg, E4, W2, b2, target, out);
}

// Round 8
// 89.159 us; speedup vs baseline: 1.2461x; 1.0228x over previous
//
#include <hip/hip_runtime.h>

#define H     300
#define MID   100
#define NN    1024
#define NP1   1025
#define JST   1088   // padded j-extent of E4 (E4[25][1088][4] floats)

typedef float v2f __attribute__((ext_vector_type(2)));
static __device__ __forceinline__ v2f sp2(float s) { return (v2f){s, s}; }
static __device__ __forceinline__ v2f fma2(v2f a, v2f b, v2f c) {
    return __builtin_elementwise_fma(a, b, c);
}

// 16-lane-row rotate-add via DPP (VALU pipe, no DS traffic).
template <int CTRL>
static __device__ __forceinline__ float row_ror_add(float v) {
    const int s = __builtin_amdgcn_update_dpp(0, __float_as_int(v), CTRL, 0xF, 0xF, true);
    return v + __int_as_float(s);
}
// Joint reduction of TWO values across a 32-lane group:
// lanes<16 end with sum(a), lanes>=16 with sum(b). Tree per value is
// bit-identical to the old red32 (xor16 pair, then ror8/4/2/1 within the
// 16-row), so results are bit-identical; cost 12 inst for 2 values vs 20.
static __device__ __forceinline__ float pair_red(float a, float b, int hb) {
    const float t = (hb < 16) ? a : b;
    const float u = (hb < 16) ? b : a;
    float v = t + __int_as_float(
        __builtin_amdgcn_ds_swizzle(__float_as_int(u), 0x401F));  // += other half
    v = row_ror_add<0x128>(v);   // row_ror:8
    v = row_ror_add<0x124>(v);   // row_ror:4
    v = row_ror_add<0x122>(v);   // row_ror:2
    v = row_ror_add<0x121>(v);   // row_ror:1
    return v;
}

// ---------------------------------------------------------------------------
// Kernel A: 256 blocks x 1024 threads; block b -> items i0=4b..4b+3.
// R5-R7 established: A is issue/latency-bound (~630 wave-inst/thread), not
// BW- or occupancy-bound. This version: (1) zero clamp-waste — 200 pairs =
// 6 full steps + step 6 for groups 0..7 only (wave-uniform: waves 4..15 skip);
// (2) joint pair-reduction (24 inst/step vs 40); (3) distance-1 W1 prefetch
// (wrow advances by a constant 16*600 floats/step; next step's 10 loads issue
// before current step's 41 FMAs). group parity = half (p = s*32+grp, s*32
// even); m = s*16 + (grp>>1). Per-dot FMA order and reduction tree are
// bit-identical to R4-R7 -> absmax must stay exactly 7.629395e-06.
// half==0 -> Fg[i*MID+m] = exp2(-s1*log2e); half==1 -> E4 column (j=item+1).
// ---------------------------------------------------------------------------
__global__ __launch_bounds__(1024, 4) void precompute_kernel(
    const float* __restrict__ sentence,
    const float* __restrict__ W1,
    const float* __restrict__ b1,
    float* __restrict__ Fg,
    float* __restrict__ E4,
    float* __restrict__ out)
{
    const int tid = threadIdx.x;
    const int i0 = blockIdx.x * 4;
    const float NL = -1.4426950408889634f;

    if (blockIdx.x == 0) {
        if (tid == 0) out[0] = 0.0f;                              // loss accumulator
        if (tid < MID)
            E4[(long)((tid >> 2) * JST) * 4 + (tid & 3)] = 1.0f;  // j=0 column
    }

    const int grp  = tid >> 5;        // 0..31 (32-lane group)
    const int hb   = tid & 31;        // h-lane within the group
    const int half = grp & 1;         // W1 half (s1 vs s2) — constant across steps

    // Loop-invariant sentence values -> registers (coalesced 128B group reads)
    const float* s0 = sentence + (long)(i0 + 0) * H + hb;
    const float* s1 = sentence + (long)(i0 + 1) * H + hb;
    const float* s2 = sentence + (long)(i0 + 2) * H + hb;
    const float* s3 = sentence + (long)(i0 + 3) * H + hb;
    float r0[10], r1[10], r2[10], r3[10];
    #pragma unroll
    for (int k = 0; k < 9; ++k) {
        r0[k] = s0[32 * k]; r1[k] = s1[32 * k];
        r2[k] = s2[32 * k]; r3[k] = s3[32 * k];
    }
    const bool tl = hb < 12;                       // tail lanes (h = 288+hb < 300)
    r0[9] = tl ? s0[288] : 0.0f;                   // predicated loads (OOB-safe)
    r1[9] = tl ? s1[288] : 0.0f;
    r2[9] = tl ? s2[288] : 0.0f;
    r3[9] = tl ? s3[288] : 0.0f;
    const int h9 = 288 + (tl ? hb : 0);            // clamped tail index (in-bounds)

    int m = grp >> 1;                              // m at step 0
    const float* wp = W1 + (long)m * (2 * H) + half * H;
    float w[10];
    #pragma unroll
    for (int k = 0; k < 9; ++k) w[k] = wp[hb + 32 * k];
    w[9] = wp[h9];

    #define ASTEP(MCUR)                                                       \
        do {                                                                  \
            float a0, a1, a2, a3;                                             \
            {                                                                 \
                const float wv = w[0];                                        \
                a0 = wv * r0[0]; a1 = wv * r1[0];                             \
                a2 = wv * r2[0]; a3 = wv * r3[0];                             \
            }                                                                 \
            _Pragma("unroll")                                                 \
            for (int k = 1; k < 9; ++k) {                                     \
                const float wv = w[k];                                        \
                a0 = __builtin_fmaf(wv, r0[k], a0);                           \
                a1 = __builtin_fmaf(wv, r1[k], a1);                           \
                a2 = __builtin_fmaf(wv, r2[k], a2);                           \
                a3 = __builtin_fmaf(wv, r3[k], a3);                           \
            }                                                                 \
            {                                                                 \
                const float wv = w[9];   /* r*[9] zeroed on non-tail lanes */ \
                a0 = __builtin_fmaf(wv, r0[9], a0);                           \
                a1 = __builtin_fmaf(wv, r1[9], a1);                           \
                a2 = __builtin_fmaf(wv, r2[9], a2);                           \
                a3 = __builtin_fmaf(wv, r3[9], a3);                           \
            }                                                                 \
            const float t01 = pair_red(a0, a1, hb);                           \
            const float t23 = pair_red(a2, a3, hb);                           \
            if ((hb & 15) == 0) {                                             \
                const int it = hb >> 4;          /* 0: items 0,2  1: 1,3 */   \
                if (half == 0) {                                              \
                    const float bb = b1[MCUR];                                \
                    Fg[(i0 + it) * MID + (MCUR)] =                            \
                        __builtin_amdgcn_exp2f((t01 + bb) * NL);              \
                    Fg[(i0 + 2 + it) * MID + (MCUR)] =                        \
                        __builtin_amdgcn_exp2f((t23 + bb) * NL);              \
                } else {                                                      \
                    float* base = E4 +                                        \
                        (long)(((MCUR) >> 2) * JST) * 4 + ((MCUR) & 3);       \
                    base[(long)(i0 + 1 + it) * 4] =                           \
                        __builtin_amdgcn_exp2f(t01 * NL);                     \
                    base[(long)(i0 + 3 + it) * 4] =                           \
                        __builtin_amdgcn_exp2f(t23 * NL);                     \
                }                                                             \
            }                                                                 \
        } while (0)

    #pragma unroll
    for (int s = 0; s < 6; ++s) {
        // prefetch step s+1 (clamped at the final partial step to stay in-bounds;
        // wave-uniform select: grp<8 <=> wave<4)
        const int mn = (s < 5 || grp < 8) ? (m + 16) : m;
        const float* wpn = W1 + (long)mn * (2 * H) + half * H;
        float wn[10];
        #pragma unroll
        for (int k = 0; k < 9; ++k) wn[k] = wpn[hb + 32 * k];
        wn[9] = wpn[h9];

        ASTEP(m);

        m = mn;
        #pragma unroll
        for (int k = 0; k < 10; ++k) w[k] = wn[k];
    }
    if (grp < 8) {           // step 6: pairs 192..199 only (waves 4..15 skip)
        ASTEP(m);
    }
    #undef ASTEP
}

// ---------------------------------------------------------------------------
// Kernel B: byte-identical to rounds 4-7 (proven neutral to all tweaks;
// est. ~3.5us, near its L2/VALU floor).
// ---------------------------------------------------------------------------
__global__ __launch_bounds__(512, 4) void main_kernel(
    const float* __restrict__ Fg,
    const float* __restrict__ E4,
    const float* __restrict__ W2,
    const float* __restrict__ b2,
    const int*   __restrict__ target,
    float* __restrict__ out)
{
    __shared__ v2f    Fq2[MID];         // {F_row0, F_row1}[m]
    __shared__ float4 w4sh[MID / 4];    // W2 m-quads
    __shared__ float  tmp[2][104];      // remainder-column partials per row
    __shared__ float  redl[8];
    __shared__ v2f    redm[8];
    __shared__ v2f    rede[8];
    __shared__ float  sc4sh[2];
    __shared__ v2f    bmax2, binv2;

    const int i0  = blockIdx.x * 2;
    const int tid = threadIdx.x;
    const int lane = tid & 63, wv = tid >> 6;
    const float L2E = 1.4426950408889634f;
    const v2f one2 = sp2(1.0f);

    if (tid < MID) {
        Fq2[tid] = (v2f){Fg[(i0 + 0) * MID + tid], Fg[(i0 + 1) * MID + tid]};
    } else if (tid >= 128 && tid < 128 + MID / 4) {
        const int p = tid - 128;
        w4sh[p] = make_float4(W2[4 * p], W2[4 * p + 1], W2[4 * p + 2], W2[4 * p + 3]);
    }
    const float b2v = b2[0];
    __syncthreads();

    // coalesced: column j reads float4 at E4 + (p*JST + j)*4
    #define LDXA(p_) (*(const float4*)(E4 + ((long)(p_) * JST + tid) * 4))
    #define LDXB(p_) (*(const float4*)(E4 + ((long)(p_) * JST + tid + 512) * 4))

    v2f acca = sp2(0.f);    // {row0,row1} for col A
    v2f accb = sp2(0.f);    // {row0,row1} for col B

    #define QCOL(X, acc)                                                      \
        do {                                                                  \
            const v2f A = fma2(sp2((X).x), F0, one2);                         \
            const v2f B = fma2(sp2((X).y), F1, one2);                         \
            const v2f C = fma2(sp2((X).z), F2, one2);                         \
            const v2f D = fma2(sp2((X).w), F3, one2);                         \
            const v2f AB = A * B, CD = C * D, P = AB * CD;                    \
            const v2f R = {__builtin_amdgcn_rcpf(P.x),                        \
                           __builtin_amdgcn_rcpf(P.y)};                       \
            const v2f n1 = fma2(w0, B, w1 * A);                               \
            const v2f n2 = fma2(w2v, D, w3 * C);                              \
            acc = fma2(fma2(n1, CD, n2 * AB), R, acc);                        \
        } while (0)

    #define QBODY(p_, XA, XB)                                                 \
        do {                                                                  \
            const v2f F0 = Fq2[4 * (p_)];                                     \
            const v2f F1 = Fq2[4 * (p_) + 1];                                 \
            const v2f F2 = Fq2[4 * (p_) + 2];                                 \
            const v2f F3 = Fq2[4 * (p_) + 3];                                 \
            const float4 w = w4sh[p_];                                        \
            const v2f w0 = sp2(w.x), w1 = sp2(w.y);                           \
            const v2f w2v = sp2(w.z), w3 = sp2(w.w);                          \
            QCOL(XA, acca);                                                   \
            QCOL(XB, accb);                                                   \
        } while (0)

    // 25 m-quads, distance-2 software pipeline on the float4 loads
    float4 xa0 = LDXA(0), xb0 = LDXB(0);
    float4 xa1 = LDXA(1), xb1 = LDXB(1);
    #pragma unroll 2
    for (int p = 0; p < 23; ++p) {
        const float4 xan = LDXA(p + 2), xbn = LDXB(p + 2);
        QBODY(p, xa0, xb0);
        xa0 = xa1; xa1 = xan;
        xb0 = xb1; xb1 = xbn;
    }
    QBODY(23, xa0, xb0);
    QBODY(24, xa1, xb1);

    const float sc0a = acca.x + b2v, sc1a = acca.y + b2v;   // col A, rows 0,1
    const float sc0b = accb.x + b2v, sc1b = accb.y + b2v;   // col B, rows 0,1

    // ---- remainder column j = 1024 (2 rows) ----
    if (tid < MID) {
        const float E = E4[((long)(tid >> 2) * JST + 1024) * 4 + (tid & 3)];
        const v2f F = Fq2[tid];
        const float wm = W2[tid];
        tmp[0][tid] = wm * __builtin_amdgcn_rcpf(__builtin_fmaf(E, F.x, 1.f));
        tmp[1][tid] = wm * __builtin_amdgcn_rcpf(__builtin_fmaf(E, F.y, 1.f));
    }
    __syncthreads();
    if (wv < 2) {
        float v = tmp[wv][lane] + ((lane < MID - 64) ? tmp[wv][lane + 64] : 0.f);
        #pragma unroll
        for (int off = 32; off > 0; off >>= 1) v += __shfl_down(v, off);
        if (lane == 0) sc4sh[wv] = v + b2v;
    }
    __syncthreads();

    // ---- loss + row-max (both columns folded per thread) ----
    const int tg0 = target[i0], tg1 = target[i0 + 1];
    const int jb = tid + 512;
    float ls = fabsf(sc0a - ((tid == tg0) ? 1.f : 0.f))
             + fabsf(sc1a - ((tid == tg1) ? 1.f : 0.f))
             + fabsf(sc0b - ((jb == tg0) ? 1.f : 0.f))
             + fabsf(sc1b - ((jb == tg1) ? 1.f : 0.f));
    v2f mx = {fmaxf(sc0a, sc0b), fmaxf(sc1a, sc1b)};
    if (tid == 0) {
        ls += fabsf(sc4sh[0] - ((1024 == tg0) ? 1.f : 0.f))
            + fabsf(sc4sh[1] - ((1024 == tg1) ? 1.f : 0.f));
        mx.x = fmaxf(mx.x, sc4sh[0]);
        mx.y = fmaxf(mx.y, sc4sh[1]);
    }
    #pragma unroll
    for (int off = 32; off > 0; off >>= 1) {
        ls += __shfl_down(ls, off);
        mx.x = fmaxf(mx.x, __shfl_down(mx.x, off));
        mx.y = fmaxf(mx.y, __shfl_down(mx.y, off));
    }
    if (lane == 0) { redl[wv] = ls; redm[wv] = mx; }
    __syncthreads();
    if (tid == 0) {
        float L = 0.f;
        v2f M = {-1e30f, -1e30f};
        #pragma unroll
        for (int k = 0; k < 8; ++k) {
            L += redl[k];
            M.x = fmaxf(M.x, redm[k].x);
            M.y = fmaxf(M.y, redm[k].y);
        }
        atomicAdd(out, L * (1.0f / ((float)NN * (float)NP1)));
        bmax2 = M;
    }
    __syncthreads();
    const v2f rm = bmax2;

    // ---- exp + sum per row (both columns) ----
    const float e0a = __builtin_amdgcn_exp2f((sc0a - rm.x) * L2E);
    const float e1a = __builtin_amdgcn_exp2f((sc1a - rm.y) * L2E);
    const float e0b = __builtin_amdgcn_exp2f((sc0b - rm.x) * L2E);
    const float e1b = __builtin_amdgcn_exp2f((sc1b - rm.y) * L2E);
    v2f e4v = sp2(0.f);
    if (tid == 0) {
        e4v.x = __builtin_amdgcn_exp2f((sc4sh[0] - rm.x) * L2E);
        e4v.y = __builtin_amdgcn_exp2f((sc4sh[1] - rm.y) * L2E);
    }
    v2f es = {e0a + e0b + e4v.x, e1a + e1b + e4v.y};
    #pragma unroll
    for (int off = 32; off > 0; off >>= 1) {
        es.x += __shfl_down(es.x, off);
        es.y += __shfl_down(es.y, off);
    }
    if (lane == 0) rede[wv] = es;
    __syncthreads();
    if (tid == 0) {
        v2f S = sp2(0.f);
        #pragma unroll
        for (int k = 0; k < 8; ++k) { S.x += rede[k].x; S.y += rede[k].y; }
        binv2 = (v2f){1.f / S.x, 1.f / S.y};
    }
    __syncthreads();
    const v2f iv = binv2;

    // ---- write softmax rows (both columns) ----
    float* o0 = out + 1 + (long)(i0 + 0) * NP1;
    float* o1 = out + 1 + (long)(i0 + 1) * NP1;
    o0[tid] = e0a * iv.x;
    o1[tid] = e1a * iv.y;
    o0[jb] = e0b * iv.x;
    o1[jb] = e1b * iv.y;
    if (tid == 0) {
        o0[1024] = e4v.x * iv.x;
        o1[1024] = e4v.y * iv.y;
    }
    #undef QBODY
    #undef QCOL
    #undef LDXA
    #undef LDXB
}

extern "C" void kernel_launch(void* const* d_in, const int* in_sizes, int n_in,
                              void* d_out, int out_size, void* d_ws, size_t ws_size,
                              hipStream_t stream) {
    const float* sentence = (const float*)d_in[0];
    const int*   target   = (const int*)  d_in[1];
    const float* W1       = (const float*)d_in[2];
    const float* b1       = (const float*)d_in[3];
    const float* W2       = (const float*)d_in[4];
    const float* b2       = (const float*)d_in[5];
    float* out = (float*)d_out;

    float* Fg = (float*)d_ws;                  // 1024*100 floats (F = exp(-s1))
    float* E4 = Fg + NN * MID;                 // 25*1088*4 floats

    precompute_kernel<<<NN / 4, 1024, 0, stream>>>(sentence, W1, b1, Fg, E4, out);
    main_kernel<<<NN / 2, 512, 0, stream>>>(Fg, E4, W2, b2, target, out);
}

// Round 9
// 88.775 us; speedup vs baseline: 1.2514x; 1.0043x over previous
//
#include <hip/hip_runtime.h>

#define H     300
#define MID   100
#define NN    1024
#define NP1   1025
#define JST   1088   // padded j-extent of E4 (E4[25][1088][4] floats)

typedef float v2f __attribute__((ext_vector_type(2)));
static __device__ __forceinline__ v2f sp2(float s) { return (v2f){s, s}; }
static __device__ __forceinline__ v2f fma2(v2f a, v2f b, v2f c) {
    return __builtin_elementwise_fma(a, b, c);
}

// 16-lane-row rotate-add via DPP (VALU pipe, no DS traffic).
template <int CTRL>
static __device__ __forceinline__ float row_ror_add(float v) {
    const int s = __builtin_amdgcn_update_dpp(0, __float_as_int(v), CTRL, 0xF, 0xF, true);
    return v + __int_as_float(s);
}
// Joint reduction of TWO values across a 32-lane group:
// lanes<16 end with sum(a), lanes>=16 with sum(b). u is lane-varying
// (u[l]=b for l<16, a for l>=16), so swz_xor16(u)[l<16]=a[l+16] — each half
// sums its own value; tree bit-identical to the original red32.
static __device__ __forceinline__ float pair_red(float a, float b, int hb) {
    const float t = (hb < 16) ? a : b;
    const float u = (hb < 16) ? b : a;
    float v = t + __int_as_float(
        __builtin_amdgcn_ds_swizzle(__float_as_int(u), 0x401F));  // += other half
    v = row_ror_add<0x128>(v);   // row_ror:8
    v = row_ror_add<0x124>(v);   // row_ror:4
    v = row_ror_add<0x122>(v);   // row_ror:2
    v = row_ror_add<0x121>(v);   // row_ror:1
    return v;
}

// ---------------------------------------------------------------------------
// Kernel A: 256 blocks x 1024 threads; block b -> items i0=4b..4b+3.
// R8 validated the issue/latency model (inst cut -> matching time cut).
// This version SOFTWARE-PIPELINES THE REDUCTION: step s's 41-FMA block is
// textually adjacent to step s-1's reduce+store (independent dataflow), so
// the ~250-cycle serial pair_red/DPP chain hides under the next step's FMAs.
// W1 prefetch stays distance-1 via a 2-slot w buffer (statically indexed
// after full unroll). Pair map unchanged: group grp owns pairs {s*32+grp},
// m = s*16 + (grp>>1), half = grp&1; 6 full steps + step 6 for grp<8.
// FMA order + reduction tree bit-identical -> absmax exactly 7.629395e-06.
// half==0 -> Fg[i*MID+m] = exp2(-s1*log2e); half==1 -> E4 column (j=item+1).
// ---------------------------------------------------------------------------
__global__ __launch_bounds__(1024, 4) void precompute_kernel(
    const float* __restrict__ sentence,
    const float* __restrict__ W1,
    const float* __restrict__ b1,
    float* __restrict__ Fg,
    float* __restrict__ E4,
    float* __restrict__ out)
{
    const int tid = threadIdx.x;
    const int i0 = blockIdx.x * 4;
    const float NL = -1.4426950408889634f;

    if (blockIdx.x == 0) {
        if (tid == 0) out[0] = 0.0f;                              // loss accumulator
        if (tid < MID)
            E4[(long)((tid >> 2) * JST) * 4 + (tid & 3)] = 1.0f;  // j=0 column
    }

    const int grp  = tid >> 5;        // 0..31 (32-lane group)
    const int hb   = tid & 31;        // h-lane within the group
    const int half = grp & 1;         // W1 half (s1 vs s2) — constant across steps

    // Loop-invariant sentence values -> registers (coalesced 128B group reads)
    const float* s0 = sentence + (long)(i0 + 0) * H + hb;
    const float* s1 = sentence + (long)(i0 + 1) * H + hb;
    const float* s2 = sentence + (long)(i0 + 2) * H + hb;
    const float* s3 = sentence + (long)(i0 + 3) * H + hb;
    float r0[10], r1[10], r2[10], r3[10];
    #pragma unroll
    for (int k = 0; k < 9; ++k) {
        r0[k] = s0[32 * k]; r1[k] = s1[32 * k];
        r2[k] = s2[32 * k]; r3[k] = s3[32 * k];
    }
    const bool tl = hb < 12;                       // tail lanes (h = 288+hb < 300)
    r0[9] = tl ? s0[288] : 0.0f;                   // predicated loads (OOB-safe)
    r1[9] = tl ? s1[288] : 0.0f;
    r2[9] = tl ? s2[288] : 0.0f;
    r3[9] = tl ? s3[288] : 0.0f;
    const int h9 = 288 + (tl ? hb : 0);            // clamped tail index (in-bounds)

    #define LOADW(WARR, MVAL)                                                 \
        do {                                                                  \
            const float* _wp = W1 + (long)(MVAL) * (2 * H) + half * H;        \
            _Pragma("unroll")                                                 \
            for (int k = 0; k < 9; ++k) (WARR)[k] = _wp[hb + 32 * k];         \
            (WARR)[9] = _wp[h9];                                              \
        } while (0)

    #define AFMA(A0, A1, A2, A3, WARR)                                        \
        do {                                                                  \
            {                                                                 \
                const float wv = (WARR)[0];                                   \
                A0 = wv * r0[0]; A1 = wv * r1[0];                             \
                A2 = wv * r2[0]; A3 = wv * r3[0];                             \
            }                                                                 \
            _Pragma("unroll")                                                 \
            for (int k = 1; k < 9; ++k) {                                     \
                const float wv = (WARR)[k];                                   \
                A0 = __builtin_fmaf(wv, r0[k], A0);                           \
                A1 = __builtin_fmaf(wv, r1[k], A1);                           \
                A2 = __builtin_fmaf(wv, r2[k], A2);                           \
                A3 = __builtin_fmaf(wv, r3[k], A3);                           \
            }                                                                 \
            {                                                                 \
                const float wv = (WARR)[9]; /* r*[9] zeroed on non-tail */    \
                A0 = __builtin_fmaf(wv, r0[9], A0);                           \
                A1 = __builtin_fmaf(wv, r1[9], A1);                           \
                A2 = __builtin_fmaf(wv, r2[9], A2);                           \
                A3 = __builtin_fmaf(wv, r3[9], A3);                           \
            }                                                                 \
        } while (0)

    #define AREDST(A0, A1, A2, A3, MCUR)                                      \
        do {                                                                  \
            const float t01 = pair_red(A0, A1, hb);                           \
            const float t23 = pair_red(A2, A3, hb);                           \
            if ((hb & 15) == 0) {                                             \
                const int it = hb >> 4;          /* 0: items 0,2  1: 1,3 */   \
                if (half == 0) {                                              \
                    const float bb = b1[MCUR];                                \
                    Fg[(i0 + it) * MID + (MCUR)] =                            \
                        __builtin_amdgcn_exp2f((t01 + bb) * NL);              \
                    Fg[(i0 + 2 + it) * MID + (MCUR)] =                        \
                        __builtin_amdgcn_exp2f((t23 + bb) * NL);              \
                } else {                                                      \
                    float* base = E4 +                                        \
                        (long)(((MCUR) >> 2) * JST) * 4 + ((MCUR) & 3);       \
                    base[(long)(i0 + 1 + it) * 4] =                           \
                        __builtin_amdgcn_exp2f(t01 * NL);                     \
                    base[(long)(i0 + 3 + it) * 4] =                           \
                        __builtin_amdgcn_exp2f(t23 * NL);                     \
                }                                                             \
            }                                                                 \
        } while (0)

    int m = grp >> 1;                  // m at step 0
    float w[2][10];                    // 2-slot prefetch buffer (static idx after unroll)
    LOADW(w[0], m);                    // step 0
    LOADW(w[1], m + 16);               // step 1 (prefetch)

    float p0, p1, p2, p3;              // pending (un-reduced) accumulators
    AFMA(p0, p1, p2, p3, w[0]);        // step 0 FMAs
    int mp = m;                        // m of pending step
    m += 16;                           // m of w[1] (current front)

    #pragma unroll
    for (int s = 1; s <= 5; ++s) {
        const int cur = s & 1;
        // prefetch step s+1 (step 6 exists only for grp<8; clamp keeps loads in-bounds)
        const int mn = (s <= 4 || grp < 8) ? (m + 16) : m;
        LOADW(w[cur ^ 1], mn);
        float c0, c1, c2, c3;
        AFMA(c0, c1, c2, c3, w[cur]);    // step s FMAs ...
        AREDST(p0, p1, p2, p3, mp);      // ... interleave with step s-1 reduce+store
        p0 = c0; p1 = c1; p2 = c2; p3 = c3;
        mp = m; m = mn;
    }
    AREDST(p0, p1, p2, p3, mp);          // step 5 reduce
    if (grp < 8) {                       // step 6: pairs 192..199 (waves 4..15 skip)
        float c0, c1, c2, c3;
        AFMA(c0, c1, c2, c3, w[0]);      // s=5 prefetched step 6 into w[0]
        AREDST(c0, c1, c2, c3, m);
    }
    #undef AREDST
    #undef AFMA
    #undef LOADW
}

// ---------------------------------------------------------------------------
// Kernel B: byte-identical to rounds 4-8 (proven neutral to all tweaks;
// ~3-4us, near its L2/issue floor).
// ---------------------------------------------------------------------------
__global__ __launch_bounds__(512, 4) void main_kernel(
    const float* __restrict__ Fg,
    const float* __restrict__ E4,
    const float* __restrict__ W2,
    const float* __restrict__ b2,
    const int*   __restrict__ target,
    float* __restrict__ out)
{
    __shared__ v2f    Fq2[MID];         // {F_row0, F_row1}[m]
    __shared__ float4 w4sh[MID / 4];    // W2 m-quads
    __shared__ float  tmp[2][104];      // remainder-column partials per row
    __shared__ float  redl[8];
    __shared__ v2f    redm[8];
    __shared__ v2f    rede[8];
    __shared__ float  sc4sh[2];
    __shared__ v2f    bmax2, binv2;

    const int i0  = blockIdx.x * 2;
    const int tid = threadIdx.x;
    const int lane = tid & 63, wv = tid >> 6;
    const float L2E = 1.4426950408889634f;
    const v2f one2 = sp2(1.0f);

    if (tid < MID) {
        Fq2[tid] = (v2f){Fg[(i0 + 0) * MID + tid], Fg[(i0 + 1) * MID + tid]};
    } else if (tid >= 128 && tid < 128 + MID / 4) {
        const int p = tid - 128;
        w4sh[p] = make_float4(W2[4 * p], W2[4 * p + 1], W2[4 * p + 2], W2[4 * p + 3]);
    }
    const float b2v = b2[0];
    __syncthreads();

    // coalesced: column j reads float4 at E4 + (p*JST + j)*4
    #define LDXA(p_) (*(const float4*)(E4 + ((long)(p_) * JST + tid) * 4))
    #define LDXB(p_) (*(const float4*)(E4 + ((long)(p_) * JST + tid + 512) * 4))

    v2f acca = sp2(0.f);    // {row0,row1} for col A
    v2f accb = sp2(0.f);    // {row0,row1} for col B

    #define QCOL(X, acc)                                                      \
        do {                                                                  \
            const v2f A = fma2(sp2((X).x), F0, one2);                         \
            const v2f B = fma2(sp2((X).y), F1, one2);                         \
            const v2f C = fma2(sp2((X).z), F2, one2);                         \
            const v2f D = fma2(sp2((X).w), F3, one2);                         \
            const v2f AB = A * B, CD = C * D, P = AB * CD;                    \
            const v2f R = {__builtin_amdgcn_rcpf(P.x),                        \
                           __builtin_amdgcn_rcpf(P.y)};                       \
            const v2f n1 = fma2(w0, B, w1 * A);                               \
            const v2f n2 = fma2(w2v, D, w3 * C);                              \
            acc = fma2(fma2(n1, CD, n2 * AB), R, acc);                        \
        } while (0)

    #define QBODY(p_, XA, XB)                                                 \
        do {                                                                  \
            const v2f F0 = Fq2[4 * (p_)];                                     \
            const v2f F1 = Fq2[4 * (p_) + 1];                                 \
            const v2f F2 = Fq2[4 * (p_) + 2];                                 \
            const v2f F3 = Fq2[4 * (p_) + 3];                                 \
            const float4 w = w4sh[p_];                                        \
            const v2f w0 = sp2(w.x), w1 = sp2(w.y);                           \
            const v2f w2v = sp2(w.z), w3 = sp2(w.w);                          \
            QCOL(XA, acca);                                                   \
            QCOL(XB, accb);                                                   \
        } while (0)

    // 25 m-quads, distance-2 software pipeline on the float4 loads
    float4 xa0 = LDXA(0), xb0 = LDXB(0);
    float4 xa1 = LDXA(1), xb1 = LDXB(1);
    #pragma unroll 2
    for (int p = 0; p < 23; ++p) {
        const float4 xan = LDXA(p + 2), xbn = LDXB(p + 2);
        QBODY(p, xa0, xb0);
        xa0 = xa1; xa1 = xan;
        xb0 = xb1; xb1 = xbn;
    }
    QBODY(23, xa0, xb0);
    QBODY(24, xa1, xb1);

    const float sc0a = acca.x + b2v, sc1a = acca.y + b2v;   // col A, rows 0,1
    const float sc0b = accb.x + b2v, sc1b = accb.y + b2v;   // col B, rows 0,1

    // ---- remainder column j = 1024 (2 rows) ----
    if (tid < MID) {
        const float E = E4[((long)(tid >> 2) * JST + 1024) * 4 + (tid & 3)];
        const v2f F = Fq2[tid];
        const float wm = W2[tid];
        tmp[0][tid] = wm * __builtin_amdgcn_rcpf(__builtin_fmaf(E, F.x, 1.f));
        tmp[1][tid] = wm * __builtin_amdgcn_rcpf(__builtin_fmaf(E, F.y, 1.f));
    }
    __syncthreads();
    if (wv < 2) {
        float v = tmp[wv][lane] + ((lane < MID - 64) ? tmp[wv][lane + 64] : 0.f);
        #pragma unroll
        for (int off = 32; off > 0; off >>= 1) v += __shfl_down(v, off);
        if (lane == 0) sc4sh[wv] = v + b2v;
    }
    __syncthreads();

    // ---- loss + row-max (both columns folded per thread) ----
    const int tg0 = target[i0], tg1 = target[i0 + 1];
    const int jb = tid + 512;
    float ls = fabsf(sc0a - ((tid == tg0) ? 1.f : 0.f))
             + fabsf(sc1a - ((tid == tg1) ? 1.f : 0.f))
             + fabsf(sc0b - ((jb == tg0) ? 1.f : 0.f))
             + fabsf(sc1b - ((jb == tg1) ? 1.f : 0.f));
    v2f mx = {fmaxf(sc0a, sc0b), fmaxf(sc1a, sc1b)};
    if (tid == 0) {
        ls += fabsf(sc4sh[0] - ((1024 == tg0) ? 1.f : 0.f))
            + fabsf(sc4sh[1] - ((1024 == tg1) ? 1.f : 0.f));
        mx.x = fmaxf(mx.x, sc4sh[0]);
        mx.y = fmaxf(mx.y, sc4sh[1]);
    }
    #pragma unroll
    for (int off = 32; off > 0; off >>= 1) {
        ls += __shfl_down(ls, off);
        mx.x = fmaxf(mx.x, __shfl_down(mx.x, off));
        mx.y = fmaxf(mx.y, __shfl_down(mx.y, off));
    }
    if (lane == 0) { redl[wv] = ls; redm[wv] = mx; }
    __syncthreads();
    if (tid == 0) {
        float L = 0.f;
        v2f M = {-1e30f, -1e30f};
        #pragma unroll
        for (int k = 0; k < 8; ++k) {
            L += redl[k];
            M.x = fmaxf(M.x, redm[k].x);
            M.y = fmaxf(M.y, redm[k].y);
        }
        atomicAdd(out, L * (1.0f / ((float)NN * (float)NP1)));
        bmax2 = M;
    }
    __syncthreads();
    const v2f rm = bmax2;

    // ---- exp + sum per row (both columns) ----
    const float e0a = __builtin_amdgcn_exp2f((sc0a - rm.x) * L2E);
    const float e1a = __builtin_amdgcn_exp2f((sc1a - rm.y) * L2E);
    const float e0b = __builtin_amdgcn_exp2f((sc0b - rm.x) * L2E);
    const float e1b = __builtin_amdgcn_exp2f((sc1b - rm.y) * L2E);
    v2f e4v = sp2(0.f);
    if (tid == 0) {
        e4v.x = __builtin_amdgcn_exp2f((sc4sh[0] - rm.x) * L2E);
        e4v.y = __builtin_amdgcn_exp2f((sc4sh[1] - rm.y) * L2E);
    }
    v2f es = {e0a + e0b + e4v.x, e1a + e1b + e4v.y};
    #pragma unroll
    for (int off = 32; off > 0; off >>= 1) {
        es.x += __shfl_down(es.x, off);
        es.y += __shfl_down(es.y, off);
    }
    if (lane == 0) rede[wv] = es;
    __syncthreads();
    if (tid == 0) {
        v2f S = sp2(0.f);
        #pragma unroll
        for (int k = 0; k < 8; ++k) { S.x += rede[k].x; S.y += rede[k].y; }
        binv2 = (v2f){1.f / S.x, 1.f / S.y};
    }
    __syncthreads();
    const v2f iv = binv2;

    // ---- write softmax rows (both columns) ----
    float* o0 = out + 1 + (long)(i0 + 0) * NP1;
    float* o1 = out + 1 + (long)(i0 + 1) * NP1;
    o0[tid] = e0a * iv.x;
    o1[tid] = e1a * iv.y;
    o0[jb] = e0b * iv.x;
    o1[jb] = e1b * iv.y;
    if (tid == 0) {
        o0[1024] = e4v.x * iv.x;
        o1[1024] = e4v.y * iv.y;
    }
    #undef QBODY
    #undef QCOL
    #undef LDXA
    #undef LDXB
}

extern "C" void kernel_launch(void* const* d_in, const int* in_sizes, int n_in,
                              void* d_out, int out_size, void* d_ws, size_t ws_size,
                              hipStream_t stream) {
    const float* sentence = (const float*)d_in[0];
    const int*   target   = (const int*)  d_in[1];
    const float* W1       = (const float*)d_in[2];
    const float* b1       = (const float*)d_in[3];
    const float* W2       = (const float*)d_in[4];
    const float* b2       = (const float*)d_in[5];
    float* out = (float*)d_out;

    float* Fg = (float*)d_ws;                  // 1024*100 floats (F = exp(-s1))
    float* E4 = Fg + NN * MID;                 // 25*1088*4 floats

    precompute_kernel<<<NN / 4, 1024, 0, stream>>>(sentence, W1, b1, Fg, E4, out);
    main_kernel<<<NN / 2, 512, 0, stream>>>(Fg, E4, W2, b2, target, out);
}